// Round 2
// baseline (151.010 us; speedup 1.0000x reference)
//
#include <hip/hip_runtime.h>

#define B_   8
#define K_   4
#define C_   512
#define M_   8
#define HW_  256
#define CM_  4096   // C_*M_

// ---------------------------------------------------------------------------
// K1: rbar[b*C + c] = mean over (k, hw) of refs[b][k][c][hw]
// One block per (b,c); 256 threads; thread t loads one float4 of the
// 4 KB (k,hw) tile (k = t>>6, hw4 = t&63), then block-reduce.
// ---------------------------------------------------------------------------
__global__ void k_rbar(const float* __restrict__ refs, float* __restrict__ rbar) {
    const int bc = blockIdx.x;          // 0..4095
    const int b  = bc >> 9;
    const int c  = bc & (C_ - 1);
    const int t  = threadIdx.x;         // 0..255
    const int k   = t >> 6;
    const int hw4 = t & 63;

    const float4* p = (const float4*)refs
                    + ((((size_t)b * K_ + k) * C_ + c) << 6) + hw4;
    const float4 v = *p;
    float s = (v.x + v.y) + (v.z + v.w);

    // wave64 reduce
#pragma unroll
    for (int off = 32; off > 0; off >>= 1)
        s += __shfl_down(s, off, 64);

    __shared__ float wsum[4];
    if ((t & 63) == 0) wsum[t >> 6] = s;
    __syncthreads();
    if (t == 0)
        rbar[bc] = (wsum[0] + wsum[1] + wsum[2] + wsum[3]) * (1.0f / (K_ * HW_));
}

// ---------------------------------------------------------------------------
// K2: vbar[b, cm] = sum_c rbar[b,c] * vW[c, cm] + vb[cm], written PERMUTED:
//     of[b*CM + m*C + ci]  where cm = ci*M + m   (head-major (m c) layout)
// grid = 128 blocks: blockIdx = b*16 + cm_chunk; 256 threads (one cm each).
// ---------------------------------------------------------------------------
__global__ void k_vbar(const float* __restrict__ rbar, const float* __restrict__ vW,
                       const float* __restrict__ vb, float* __restrict__ of) {
    const int blk   = blockIdx.x;       // 0..127
    const int b     = blk >> 4;
    const int chunk = blk & 15;
    const int t     = threadIdx.x;      // 0..255
    const int cm    = chunk * 256 + t;

    __shared__ float rb[C_];
    for (int i = t; i < C_; i += 256) rb[i] = rbar[b * C_ + i];
    __syncthreads();

    float acc = 0.f;
#pragma unroll 8
    for (int c = 0; c < C_; ++c)
        acc += rb[c] * vW[(size_t)c * CM_ + cm];   // coalesced across threads

    const int ci = cm >> 3;             // cm = ci*M + m  (M=8)
    const int m  = cm & 7;
    of[b * CM_ + m * C_ + ci] = acc + vb[cm];
}

// ---------------------------------------------------------------------------
// K3: res_vec[b, co] += sum_{j in chunk} of[b, j] * fcW[j, co]
// grid = 64 blocks: blockIdx = b*8 + jchunk; 512 threads (one co each).
// res_vec zeroed beforehand (hipMemsetAsync).
// ---------------------------------------------------------------------------
__global__ void k_res(const float* __restrict__ of, const float* __restrict__ fcW,
                      float* __restrict__ res_vec) {
    const int b  = blockIdx.x >> 3;
    const int jc = blockIdx.x & 7;
    const int t  = threadIdx.x;         // co, 0..511

    __shared__ float lof[512];
    lof[t] = of[b * CM_ + jc * 512 + t];
    __syncthreads();

    float acc = 0.f;
#pragma unroll 8
    for (int j = 0; j < 512; ++j)
        acc += lof[j] * fcW[(size_t)(jc * 512 + j) * C_ + t];  // coalesced

    atomicAdd(&res_vec[b * C_ + t], acc);
}

// ---------------------------------------------------------------------------
// K4: out[b][ch][hw] = ch < 512 ? res_vec[b,ch] + fcb[ch]
//                               : content[b][ch-512][hw]
// float4-vectorized; 524288 float4s total.
// ---------------------------------------------------------------------------
__global__ void k_out(const float* __restrict__ res_vec, const float* __restrict__ fcb,
                      const float* __restrict__ content, float4* __restrict__ out4) {
    const int i = blockIdx.x * 256 + threadIdx.x;  // 0..524287
    const int hw4 = i & 63;                        // 64 float4 per (b,ch)
    const int ch  = (i >> 6) & 1023;
    const int b   = i >> 16;

    if (ch < C_) {
        const float v = res_vec[b * C_ + ch] + fcb[ch];
        out4[i] = make_float4(v, v, v, v);
    } else {
        const float4* c4 = (const float4*)content;
        out4[i] = c4[(((size_t)b * C_ + (ch - C_)) << 6) + hw4];
    }
}

// ---------------------------------------------------------------------------
extern "C" void kernel_launch(void* const* d_in, const int* in_sizes, int n_in,
                              void* d_out, int out_size, void* d_ws, size_t ws_size,
                              hipStream_t stream) {
    const float* content = (const float*)d_in[0];
    const float* refs    = (const float*)d_in[1];
    // d_in[2..5] = qW, qb, kW, kb — provably irrelevant: scale 512^4 makes
    // softmax uniform to within ~1e-10 per weight (error ~1e-12 at the output).
    const float* vW  = (const float*)d_in[6];
    const float* vb  = (const float*)d_in[7];
    const float* fcW = (const float*)d_in[8];
    const float* fcb = (const float*)d_in[9];

    float* ws      = (float*)d_ws;
    float* rbar    = ws;                    // 4096 floats
    float* of      = ws + 4096;             // 8*4096 = 32768 floats (permuted vbar)
    float* res_vec = ws + 4096 + 32768;     // 4096 floats

    hipMemsetAsync(res_vec, 0, 4096 * sizeof(float), stream);

    k_rbar<<<B_ * C_, 256, 0, stream>>>(refs, rbar);
    k_vbar<<<128, 256, 0, stream>>>(rbar, vW, vb, of);
    k_res <<<64, 512, 0, stream>>>(of, fcW, res_vec);
    k_out <<<(B_ * 1024 * HW_ / 4) / 256, 256, 0, stream>>>(res_vec, fcb, content,
                                                            (float4*)d_out);
}

// Round 3
// 124.750 us; speedup vs baseline: 1.2105x; 1.2105x over previous
//
#include <hip/hip_runtime.h>

#define B_   8
#define K_   4
#define C_   512
#define M_   8
#define HW_  256
#define CM_  4096   // C_*M_

// ---------------------------------------------------------------------------
// K1: rbar[b*C + c] = mean over (k, hw) of refs[b][k][c][hw]
// One block per (b,c); 256 threads; thread t loads one float4 of the
// 4 KB (k,hw) tile (k = t>>6, hw4 = t&63), then block-reduce.
// ---------------------------------------------------------------------------
__global__ void k_rbar(const float* __restrict__ refs, float* __restrict__ rbar) {
    const int bc = blockIdx.x;          // 0..4095
    const int b  = bc >> 9;
    const int c  = bc & (C_ - 1);
    const int t  = threadIdx.x;         // 0..255
    const int k   = t >> 6;
    const int hw4 = t & 63;

    const float4* p = (const float4*)refs
                    + ((((size_t)b * K_ + k) * C_ + c) << 6) + hw4;
    const float4 v = *p;
    float s = (v.x + v.y) + (v.z + v.w);

#pragma unroll
    for (int off = 32; off > 0; off >>= 1)
        s += __shfl_down(s, off, 64);

    __shared__ float wsum[4];
    if ((t & 63) == 0) wsum[t >> 6] = s;
    __syncthreads();
    if (t == 0)
        rbar[bc] = (wsum[0] + wsum[1] + wsum[2] + wsum[3]) * (1.0f / (K_ * HW_));
}

// ---------------------------------------------------------------------------
// K2: vbar[b, cm] += sum_{c in seg} rbar[b,c] * vW[c, cm]  (+ vb[cm] on seg 0)
// K-split GEMV: grid = 8 b x 4 cm-tiles x 16 c-segments = 512 blocks.
// Each thread owns 4 consecutive cm (float4 loads of vW); 32 c per segment.
// vbar must be zeroed beforehand. Unpermuted (c m) layout.
// ---------------------------------------------------------------------------
__global__ void k_vbar(const float* __restrict__ rbar, const float* __restrict__ vW,
                       const float* __restrict__ vb, float* __restrict__ vbar) {
    const int blk  = blockIdx.x;        // 0..511
    const int b    = blk >> 6;
    const int tile = (blk >> 4) & 3;    // 0..3  (1024 cm each)
    const int seg  = blk & 15;          // 0..15 (32 c each)
    const int t    = threadIdx.x;       // 0..255

    __shared__ float rb[32];
    if (t < 32) rb[t] = rbar[b * C_ + seg * 32 + t];
    __syncthreads();

    const float4* vW4 = (const float4*)vW;   // row c has 1024 float4
    const int col4 = tile * 256 + t;          // float4 column index

    float4 acc = make_float4(0.f, 0.f, 0.f, 0.f);
#pragma unroll 8
    for (int c = 0; c < 32; ++c) {
        const float4 w = vW4[(size_t)(seg * 32 + c) * 1024 + col4];
        const float r = rb[c];
        acc.x += r * w.x; acc.y += r * w.y; acc.z += r * w.z; acc.w += r * w.w;
    }
    if (seg == 0) {
        const float4 bb = ((const float4*)vb)[col4];
        acc.x += bb.x; acc.y += bb.y; acc.z += bb.z; acc.w += bb.w;
    }
    float* dst = vbar + (size_t)b * CM_ + col4 * 4;
    atomicAdd(dst + 0, acc.x);
    atomicAdd(dst + 1, acc.y);
    atomicAdd(dst + 2, acc.z);
    atomicAdd(dst + 3, acc.w);
}

// ---------------------------------------------------------------------------
// K3: res_vec[b, co] += sum_{cm in seg} vbar[b,cm] * fcW[perm(cm), co]
// perm(cm) = (cm&7)*C + (cm>>3)  -- the (m c) head-major concat, folded into
// the row index (row order in a sum is arbitrary; rows stay contiguous).
// grid = 8 b x 32 segments = 256 blocks; 256 threads, 2 co each (float2).
// res_vec must be zeroed beforehand.
// ---------------------------------------------------------------------------
__global__ void k_res(const float* __restrict__ vbar, const float* __restrict__ fcW,
                      float* __restrict__ res_vec) {
    const int b   = blockIdx.x >> 5;
    const int seg = blockIdx.x & 31;    // 128 cm each
    const int t   = threadIdx.x;        // 0..255

    __shared__ float lof[128];
    if (t < 128) lof[t] = vbar[(size_t)b * CM_ + seg * 128 + t];
    __syncthreads();

    const float2* fcW2 = (const float2*)fcW;  // row has 256 float2
    float2 acc = make_float2(0.f, 0.f);
#pragma unroll 8
    for (int j = 0; j < 128; ++j) {
        const int cm  = seg * 128 + j;
        const int row = (cm & 7) * C_ + (cm >> 3);
        const float2 w = fcW2[(size_t)row * 256 + t];
        const float v = lof[j];
        acc.x += v * w.x; acc.y += v * w.y;
    }
    float* dst = res_vec + b * C_ + t * 2;
    atomicAdd(dst + 0, acc.x);
    atomicAdd(dst + 1, acc.y);
}

// ---------------------------------------------------------------------------
// K4: out[b][ch][hw] = ch < 512 ? res_vec[b,ch] + fcb[ch]
//                               : content[b][ch-512][hw]
// ---------------------------------------------------------------------------
__global__ void k_out(const float* __restrict__ res_vec, const float* __restrict__ fcb,
                      const float* __restrict__ content, float4* __restrict__ out4) {
    const int i = blockIdx.x * 256 + threadIdx.x;  // 0..524287
    const int hw4 = i & 63;
    const int ch  = (i >> 6) & 1023;
    const int b   = i >> 16;

    if (ch < C_) {
        const float v = res_vec[b * C_ + ch] + fcb[ch];
        out4[i] = make_float4(v, v, v, v);
    } else {
        const float4* c4 = (const float4*)content;
        out4[i] = c4[(((size_t)b * C_ + (ch - C_)) << 6) + hw4];
    }
}

// ---------------------------------------------------------------------------
extern "C" void kernel_launch(void* const* d_in, const int* in_sizes, int n_in,
                              void* d_out, int out_size, void* d_ws, size_t ws_size,
                              hipStream_t stream) {
    const float* content = (const float*)d_in[0];
    const float* refs    = (const float*)d_in[1];
    // d_in[2..5] = qW, qb, kW, kb — provably irrelevant: scale 512^4 makes
    // softmax uniform to within ~1e-10 per weight (verified: absmax 4.8e-7).
    const float* vW  = (const float*)d_in[6];
    const float* vb  = (const float*)d_in[7];
    const float* fcW = (const float*)d_in[8];
    const float* fcb = (const float*)d_in[9];

    float* ws      = (float*)d_ws;
    float* rbar    = ws;                    // 4096 floats
    float* vbar    = ws + 4096;             // 32768 floats (unpermuted)
    float* res_vec = ws + 4096 + 32768;     // 4096 floats

    // zero the two atomic accumulators (contiguous) in one memset
    hipMemsetAsync(vbar, 0, (32768 + 4096) * sizeof(float), stream);

    k_rbar<<<B_ * C_, 256, 0, stream>>>(refs, rbar);
    k_vbar<<<512, 256, 0, stream>>>(rbar, vW, vb, vbar);
    k_res <<<256, 256, 0, stream>>>(vbar, fcW, res_vec);
    k_out <<<(B_ * 1024 * HW_ / 4) / 256, 256, 0, stream>>>(res_vec, fcb, content,
                                                            (float4*)d_out);
}

// Round 4
// 122.764 us; speedup vs baseline: 1.2301x; 1.0162x over previous
//
#include <hip/hip_runtime.h>

#define B_   8
#define K_   4
#define C_   512
#define M_   8
#define HW_  256
#define CM_  4096   // C_*M_

// ---------------------------------------------------------------------------
// K1: rbar[b*C + c] = mean over (k, hw) of refs[b][k][c][hw]
// One block per (b,c); 256 threads; thread t loads one float4 of the
// 4 KB (k,hw) tile. ALSO zeroes the vbar/res_vec atomic accumulators
// (36864 floats) using the first 144 blocks' threads — removes the
// separate hipMemsetAsync dispatch (stream order covers the dependency).
// ---------------------------------------------------------------------------
__global__ void k_rbar(const float* __restrict__ refs, float* __restrict__ rbar,
                       float* __restrict__ acc_zero /* vbar..res_vec, 36864 f */) {
    const int bc = blockIdx.x;          // 0..4095
    const int t  = threadIdx.x;         // 0..255

    const int g = bc * 256 + t;
    if (g < (CM_ * B_ + C_ * B_))       // 32768 + 4096 = 36864
        acc_zero[g] = 0.f;

    const int b  = bc >> 9;
    const int c  = bc & (C_ - 1);
    const int k   = t >> 6;
    const int hw4 = t & 63;

    const float4* p = (const float4*)refs
                    + ((((size_t)b * K_ + k) * C_ + c) << 6) + hw4;
    const float4 v = *p;
    float s = (v.x + v.y) + (v.z + v.w);

#pragma unroll
    for (int off = 32; off > 0; off >>= 1)
        s += __shfl_down(s, off, 64);

    __shared__ float wsum[4];
    if ((t & 63) == 0) wsum[t >> 6] = s;
    __syncthreads();
    if (t == 0)
        rbar[bc] = (wsum[0] + wsum[1] + wsum[2] + wsum[3]) * (1.0f / (K_ * HW_));
}

// ---------------------------------------------------------------------------
// K2: vbar[b, cm] += sum_{c in seg} rbar[b,c] * vW[c, cm]  (+ vb[cm] on seg 0)
// K-split GEMV: grid = 8 b x 4 cm-tiles x 16 c-segments = 512 blocks.
// Each thread owns 4 consecutive cm (float4 loads of vW); 32 c per segment.
// vbar zeroed by k_rbar. Unpermuted (c m) layout.
// ---------------------------------------------------------------------------
__global__ void k_vbar(const float* __restrict__ rbar, const float* __restrict__ vW,
                       const float* __restrict__ vb, float* __restrict__ vbar) {
    const int blk  = blockIdx.x;        // 0..511
    const int b    = blk >> 6;
    const int tile = (blk >> 4) & 3;    // 0..3  (1024 cm each)
    const int seg  = blk & 15;          // 0..15 (32 c each)
    const int t    = threadIdx.x;       // 0..255

    __shared__ float rb[32];
    if (t < 32) rb[t] = rbar[b * C_ + seg * 32 + t];
    __syncthreads();

    const float4* vW4 = (const float4*)vW;   // row c has 1024 float4
    const int col4 = tile * 256 + t;          // float4 column index

    float4 acc = make_float4(0.f, 0.f, 0.f, 0.f);
#pragma unroll 8
    for (int c = 0; c < 32; ++c) {
        const float4 w = vW4[(size_t)(seg * 32 + c) * 1024 + col4];
        const float r = rb[c];
        acc.x += r * w.x; acc.y += r * w.y; acc.z += r * w.z; acc.w += r * w.w;
    }
    if (seg == 0) {
        const float4 bb = ((const float4*)vb)[col4];
        acc.x += bb.x; acc.y += bb.y; acc.z += bb.z; acc.w += bb.w;
    }
    float* dst = vbar + (size_t)b * CM_ + col4 * 4;
    atomicAdd(dst + 0, acc.x);
    atomicAdd(dst + 1, acc.y);
    atomicAdd(dst + 2, acc.z);
    atomicAdd(dst + 3, acc.w);
}

// ---------------------------------------------------------------------------
// K3: res_vec[b, co] += sum_{cm in seg} vbar[b,cm] * fcW[perm(cm), co]
// perm(cm) = (cm&7)*C + (cm>>3)  -- the (m c) head-major concat, folded into
// the row index (row order in a sum is arbitrary; rows stay contiguous).
// grid = 8 b x 32 segments = 256 blocks; 256 threads, 2 co each (float2).
// res_vec zeroed by k_rbar.
// ---------------------------------------------------------------------------
__global__ void k_res(const float* __restrict__ vbar, const float* __restrict__ fcW,
                      float* __restrict__ res_vec) {
    const int b   = blockIdx.x >> 5;
    const int seg = blockIdx.x & 31;    // 128 cm each
    const int t   = threadIdx.x;        // 0..255

    __shared__ float lof[128];
    if (t < 128) lof[t] = vbar[(size_t)b * CM_ + seg * 128 + t];
    __syncthreads();

    const float2* fcW2 = (const float2*)fcW;  // row has 256 float2
    float2 acc = make_float2(0.f, 0.f);
#pragma unroll 8
    for (int j = 0; j < 128; ++j) {
        const int cm  = seg * 128 + j;
        const int row = (cm & 7) * C_ + (cm >> 3);
        const float2 w = fcW2[(size_t)row * 256 + t];
        const float v = lof[j];
        acc.x += v * w.x; acc.y += v * w.y;
    }
    float* dst = res_vec + b * C_ + t * 2;
    atomicAdd(dst + 0, acc.x);
    atomicAdd(dst + 1, acc.y);
}

// ---------------------------------------------------------------------------
// K4: out[b][ch][hw] = ch < 512 ? res_vec[b,ch] + fcb[ch]
//                               : content[b][ch-512][hw]
// ---------------------------------------------------------------------------
__global__ void k_out(const float* __restrict__ res_vec, const float* __restrict__ fcb,
                      const float* __restrict__ content, float4* __restrict__ out4) {
    const int i = blockIdx.x * 256 + threadIdx.x;  // 0..524287
    const int hw4 = i & 63;
    const int ch  = (i >> 6) & 1023;
    const int b   = i >> 16;

    if (ch < C_) {
        const float v = res_vec[b * C_ + ch] + fcb[ch];
        out4[i] = make_float4(v, v, v, v);
    } else {
        const float4* c4 = (const float4*)content;
        out4[i] = c4[(((size_t)b * C_ + (ch - C_)) << 6) + hw4];
    }
}

// ---------------------------------------------------------------------------
extern "C" void kernel_launch(void* const* d_in, const int* in_sizes, int n_in,
                              void* d_out, int out_size, void* d_ws, size_t ws_size,
                              hipStream_t stream) {
    const float* content = (const float*)d_in[0];
    const float* refs    = (const float*)d_in[1];
    // d_in[2..5] = qW, qb, kW, kb — provably irrelevant: scale 512^4 makes
    // softmax uniform to within ~1e-10 per weight (verified: absmax 1.2e-7).
    const float* vW  = (const float*)d_in[6];
    const float* vb  = (const float*)d_in[7];
    const float* fcW = (const float*)d_in[8];
    const float* fcb = (const float*)d_in[9];

    float* ws      = (float*)d_ws;
    float* rbar    = ws;                    // 4096 floats
    float* vbar    = ws + 4096;             // 32768 floats (unpermuted)
    float* res_vec = ws + 4096 + 32768;     // 4096 floats

    k_rbar<<<B_ * C_, 256, 0, stream>>>(refs, rbar, vbar /* zeroes vbar+res_vec */);
    k_vbar<<<512, 256, 0, stream>>>(rbar, vW, vb, vbar);
    k_res <<<256, 256, 0, stream>>>(vbar, fcW, res_vec);
    k_out <<<(B_ * 1024 * HW_ / 4) / 256, 256, 0, stream>>>(res_vec, fcb, content,
                                                            (float4*)d_out);
}